// Round 4
// baseline (735.555 us; speedup 1.0000x reference)
//
#include <hip/hip_runtime.h>
#include <hip/hip_bf16.h>

#define NN 50000
#define EE 600000
#define HH 128
#define OUTD 32
#define RR 64
#define BB 16
#define KK 2048   // BB*HH
#define NPB 16    // nodes per fused block (50000 = 16 * 3125 exactly)
#define STRB 4112 // LDS agg row stride bytes (4096+16): conflict-free MFMA A reads
#define SC_B ((NN + 1023) / 1024)  // 49 scan chunks
#define DEGB 64   // degree buckets (clamped)

typedef short s16x8 __attribute__((ext_vector_type(8)));
typedef float f32x4 __attribute__((ext_vector_type(4)));
typedef unsigned short ushort_t;
typedef unsigned int uint_t;

__device__ inline ushort_t f_to_bf16(float f){
    __hip_bfloat16 h = __float2bfloat16(f);
    return *reinterpret_cast<ushort_t*>(&h);
}
__device__ inline uint_t pack_bf16x2(float a, float b){
    return (uint_t)f_to_bf16(a) | ((uint_t)f_to_bf16(b) << 16);
}
__device__ inline float bf16_lo(uint_t u){ return __uint_as_float(u << 16); }
__device__ inline float bf16_hi(uint_t u){ return __uint_as_float(u & 0xffff0000u); }

__global__ void zero_i32(int* p, int n){
    int i = blockIdx.x*256 + threadIdx.x;
    if (i < n) p[i] = 0;
}

__global__ void hist_kernel(const int* __restrict__ dst, int* counts){
    int e = blockIdx.x*256 + threadIdx.x;
    if (e < EE) atomicAdd(&counts[dst[e]], 1);
}

// ---- hierarchical scan: chunk totals -> scan totals -> final ----
__global__ void scan_part(const int* __restrict__ counts, int* __restrict__ tot){
    int b = blockIdx.x, t = threadIdx.x;
    int i0 = b*1024 + t*4;
    int s = 0;
    if (i0 + 3 < NN){
        int4 v = *reinterpret_cast<const int4*>(&counts[i0]);
        s = v.x + v.y + v.z + v.w;
    } else {
        for (int j = 0; j < 4; j++) if (i0 + j < NN) s += counts[i0 + j];
    }
    #pragma unroll
    for (int off = 32; off; off >>= 1) s += __shfl_xor(s, off, 64);
    __shared__ int ws[4];
    if ((t & 63) == 0) ws[t >> 6] = s;
    __syncthreads();
    if (t == 0) tot[b] = ws[0] + ws[1] + ws[2] + ws[3];
}

__global__ void scan_tot(int* tot){  // 1 block, 64 threads (SC_B <= 64)
    int t = threadIdx.x;
    int v = (t < SC_B) ? tot[t] : 0;
    int x = v;
    #pragma unroll
    for (int off = 1; off < 64; off <<= 1){
        int y = __shfl_up(x, off, 64);
        if (t >= off) x += y;
    }
    if (t < SC_B) tot[t] = x - v;  // exclusive base per chunk
}

__global__ void scan_final(const int* __restrict__ counts, const int* __restrict__ tot,
                           int* __restrict__ offsets, int* __restrict__ cursor){
    int b = blockIdx.x, t = threadIdx.x, lane = t & 63, wv = t >> 6;
    int i0 = b*1024 + t*4;
    int v[4]; int s = 0;
    #pragma unroll
    for (int j = 0; j < 4; j++){ v[j] = (i0 + j < NN) ? counts[i0 + j] : 0; s += v[j]; }
    int x = s;
    #pragma unroll
    for (int off = 1; off < 64; off <<= 1){
        int y = __shfl_up(x, off, 64);
        if (lane >= off) x += y;
    }
    __shared__ int ws[4];
    if (lane == 63) ws[wv] = x;
    __syncthreads();
    int pre = tot[b];
    for (int i = 0; i < wv; i++) pre += ws[i];
    int run = pre + x - s;  // exclusive start of this thread's 4 elems
    #pragma unroll
    for (int j = 0; j < 4; j++){
        if (i0 + j < NN){
            cursor[i0 + j] = run;
            offsets[i0 + j + 1] = run + v[j];
        }
        run += v[j];
    }
    if (b == 0 && t == 0) offsets[0] = 0;
}

// scatter edge payload sorted by dst: meta[r] = {src, etype, norm_bits, 0}
__global__ void scatter_kernel(const int* __restrict__ dst, const int* __restrict__ src,
                               const int* __restrict__ etype, const float* __restrict__ norm,
                               int* cursor, int4* __restrict__ meta){
    int e = blockIdx.x*256 + threadIdx.x;
    if (e >= EE) return;
    int d = dst[e];
    int r = atomicAdd(&cursor[d], 1);
    int4 m;
    m.x = src[e];
    m.y = etype[e];
    m.z = __float_as_int(norm[e]);
    m.w = 0;
    meta[r] = m;
}

// ---- degree bucket sort: perm groups nodes of equal (clamped) degree ----
__global__ void deg_hist_kernel(const int* __restrict__ counts, int* dhist){
    int v = blockIdx.x*256 + threadIdx.x;
    if (v < NN) atomicAdd(&dhist[min(counts[v], DEGB-1)], 1);
}
__global__ void deg_scan_kernel(const int* __restrict__ dhist, int* __restrict__ dcur){
    int t = threadIdx.x;  // 64 threads
    int v = dhist[t];
    int x = v;
    #pragma unroll
    for (int off = 1; off < 64; off <<= 1){
        int y = __shfl_up(x, off, 64);
        if (t >= off) x += y;
    }
    dcur[t] = x - v;  // exclusive base
}
__global__ void deg_scatter_kernel(const int* __restrict__ counts, int* dcur,
                                   int* __restrict__ perm){
    int v = blockIdx.x*256 + threadIdx.x;
    if (v < NN){
        int d = min(counts[v], DEGB-1);
        perm[atomicAdd(&dcur[d], 1)] = v;
    }
}

// transposed bf16 weights: Wt1[o][k] = V1[k][o] (k = b*H+i), Wt2[o][k] = V2[k][o]
__global__ void convw_kernel(const float* __restrict__ V1, const float* __restrict__ V2,
                             ushort_t* __restrict__ Wt1, ushort_t* __restrict__ Wt2){
    int i = blockIdx.x*256 + threadIdx.x;
    if (i < HH*KK){
        int o = i / KK, k = i % KK;
        Wt1[i] = f_to_bf16(V1[(size_t)k*HH + o]);
    } else {
        int j = i - HH*KK;
        if (j < OUTD*KK){
            int o = j / KK, k = j % KK;
            Wt2[j] = f_to_bf16(V2[(size_t)k*OUTD + o]);
        }
    }
}

__global__ void conv_emb(const float* __restrict__ emb, ushort_t* __restrict__ xb){
    int i = blockIdx.x*256 + threadIdx.x;
    if (i < NN*HH/2){
        float2 f = *reinterpret_cast<const float2*>(emb + 2*(size_t)i);
        *reinterpret_cast<uint_t*>(xb + 2*(size_t)i) = pack_bf16x2(f.x, f.y);
    }
}

// Fused per 16 (degree-matched) nodes: wave w gathers node perm[v0+w] into LDS
// bf16 row, then MFMA vs Wt. NOUT=128: wave -> (ct=w&7, kp=w>>3), K halves,
// reduce via LDS. NOUT=32: wave -> (nt=w&1, kp=w>>1), 8 K-parts, reduce via LDS.
template<int NOUT, bool RELU, bool OUT_BF16>
__global__ __launch_bounds__(1024, 8) void fused_layer(
    const ushort_t* __restrict__ xin, const int4* __restrict__ meta,
    const int* __restrict__ offsets, const int* __restrict__ perm,
    const float* __restrict__ comp, const ushort_t* __restrict__ Wt,
    const float* __restrict__ bias, void* __restrict__ yout)
{
    __shared__ __align__(16) char aggS[NPB * STRB];
    __shared__ int nodeS[NPB];

    int tid = threadIdx.x;
    int w = tid >> 6, lane = tid & 63;
    int v0 = blockIdx.x * NPB;
    int v = perm[v0 + w];
    if (lane == 0) nodeS[w] = v;

    // ---- gather: wave w owns node v; 4 independent meta->x chains in flight ----
    float a0[BB], a1[BB];
    #pragma unroll
    for (int b = 0; b < BB; b++){ a0[b] = 0.f; a1[b] = 0.f; }
    {
        int p = offsets[v], end = offsets[v+1];
        for (; p + 3 < end; p += 4){
            int4 mm0 = meta[p];
            int4 mm1 = meta[p+1];
            int4 mm2 = meta[p+2];
            int4 mm3 = meta[p+3];
            int s0 = __builtin_amdgcn_readfirstlane(mm0.x);
            int s1 = __builtin_amdgcn_readfirstlane(mm1.x);
            int s2 = __builtin_amdgcn_readfirstlane(mm2.x);
            int s3 = __builtin_amdgcn_readfirstlane(mm3.x);
            uint_t u0 = *reinterpret_cast<const uint_t*>(xin + (size_t)s0*HH + 2*lane);
            uint_t u1 = *reinterpret_cast<const uint_t*>(xin + (size_t)s1*HH + 2*lane);
            uint_t u2 = *reinterpret_cast<const uint_t*>(xin + (size_t)s2*HH + 2*lane);
            uint_t u3 = *reinterpret_cast<const uint_t*>(xin + (size_t)s3*HH + 2*lane);
            int e0 = __builtin_amdgcn_readfirstlane(mm0.y);
            int e1 = __builtin_amdgcn_readfirstlane(mm1.y);
            int e2 = __builtin_amdgcn_readfirstlane(mm2.y);
            int e3 = __builtin_amdgcn_readfirstlane(mm3.y);
            float n0 = __int_as_float(__builtin_amdgcn_readfirstlane(mm0.z));
            float n1 = __int_as_float(__builtin_amdgcn_readfirstlane(mm1.z));
            float n2 = __int_as_float(__builtin_amdgcn_readfirstlane(mm2.z));
            float n3 = __int_as_float(__builtin_amdgcn_readfirstlane(mm3.z));
            const float* c0 = comp + e0*BB;  // SGPR base -> scalar loads
            const float* c1 = comp + e1*BB;
            const float* c2 = comp + e2*BB;
            const float* c3 = comp + e3*BB;
            float xa0 = bf16_lo(u0)*n0, xb0 = bf16_hi(u0)*n0;
            float xa1 = bf16_lo(u1)*n1, xb1 = bf16_hi(u1)*n1;
            float xa2 = bf16_lo(u2)*n2, xb2 = bf16_hi(u2)*n2;
            float xa3 = bf16_lo(u3)*n3, xb3 = bf16_hi(u3)*n3;
            #pragma unroll
            for (int b = 0; b < BB; b++){
                a0[b] = fmaf(c0[b], xa0, a0[b]);
                a1[b] = fmaf(c0[b], xb0, a1[b]);
                a0[b] = fmaf(c1[b], xa1, a0[b]);
                a1[b] = fmaf(c1[b], xb1, a1[b]);
                a0[b] = fmaf(c2[b], xa2, a0[b]);
                a1[b] = fmaf(c2[b], xb2, a1[b]);
                a0[b] = fmaf(c3[b], xa3, a0[b]);
                a1[b] = fmaf(c3[b], xb3, a1[b]);
            }
        }
        for (; p < end; ++p){
            int4 m0 = meta[p];
            int  s0 = __builtin_amdgcn_readfirstlane(m0.x);
            int  e0 = __builtin_amdgcn_readfirstlane(m0.y);
            float n0 = __int_as_float(__builtin_amdgcn_readfirstlane(m0.z));
            uint_t u0 = *reinterpret_cast<const uint_t*>(xin + (size_t)s0*HH + 2*lane);
            const float* c0 = comp + e0*BB;
            float xa0 = bf16_lo(u0)*n0, xb0 = bf16_hi(u0)*n0;
            #pragma unroll
            for (int b = 0; b < BB; b++){
                a0[b] = fmaf(c0[b], xa0, a0[b]);
                a1[b] = fmaf(c0[b], xb0, a1[b]);
            }
        }
    }
    // LDS row w: agg[w][b*128 + 2*lane..+1] packed bf16x2
    {
        char* rowp = aggS + w * STRB;
        #pragma unroll
        for (int b = 0; b < BB; b++)
            *reinterpret_cast<uint_t*>(rowp + b*256 + lane*4) = pack_bf16x2(a0[b], a1[b]);
    }
    __syncthreads();

    // ---- GEMM phase ----
    int lane15 = lane & 15;
    int kc = (lane >> 4) * 8;
    float* partS = reinterpret_cast<float*>(aggS);  // aliased AFTER MFMA reads + sync

    if (NOUT == HH){
        int ct = w & 7, kp = w >> 3;           // 8 col-tiles x 2 K-halves (K=1024)
        f32x4 acc;
        #pragma unroll
        for (int j = 0; j < 4; j++) acc[j] = 0.f;
        const ushort_t* wrow = Wt + (size_t)(ct*16 + lane15)*KK + kp*1024 + kc;
        const char* ap = aggS + lane15*STRB + (kp*1024 + kc)*2;
        #pragma unroll 4
        for (int k = 0; k < 1024; k += 32){
            s16x8 a = *reinterpret_cast<const s16x8*>(ap + k*2);
            s16x8 b = *reinterpret_cast<const s16x8*>(wrow + k);
            acc = __builtin_amdgcn_mfma_f32_16x16x32_bf16(a, b, acc, 0, 0, 0);
        }
        __syncthreads();
        if (kp == 1){
            #pragma unroll
            for (int r = 0; r < 4; r++){
                int idx = ((lane >> 4)*4 + r)*16 + lane15;
                partS[ct*256 + idx] = acc[r];
            }
        }
        __syncthreads();
        if (kp == 0){
            int col = ct*16 + lane15;
            float bv = bias[col];
            #pragma unroll
            for (int r = 0; r < 4; r++){
                int row = (lane >> 4)*4 + r;
                int idx = row*16 + lane15;
                int node = nodeS[row];
                float val = acc[r] + partS[ct*256 + idx] + bv;
                if (RELU) val = fmaxf(val, 0.f);
                if (OUT_BF16)
                    reinterpret_cast<ushort_t*>(yout)[(size_t)node*NOUT + col] = f_to_bf16(val);
                else
                    reinterpret_cast<float*>(yout)[(size_t)node*NOUT + col] = val;
            }
        }
    } else {
        int nt = w & 1, kp = w >> 1;           // 2 col-tiles x 8 K-parts (K=256)
        f32x4 acc;
        #pragma unroll
        for (int j = 0; j < 4; j++) acc[j] = 0.f;
        const ushort_t* wrow = Wt + (size_t)(nt*16 + lane15)*KK + kp*256 + kc;
        const char* ap = aggS + lane15*STRB + (kp*256 + kc)*2;
        #pragma unroll
        for (int k = 0; k < 256; k += 32){
            s16x8 a = *reinterpret_cast<const s16x8*>(ap + k*2);
            s16x8 b = *reinterpret_cast<const s16x8*>(wrow + k);
            acc = __builtin_amdgcn_mfma_f32_16x16x32_bf16(a, b, acc, 0, 0, 0);
        }
        __syncthreads();
        #pragma unroll
        for (int r = 0; r < 4; r++){
            int idx = ((lane >> 4)*4 + r)*16 + lane15;
            partS[w*256 + idx] = acc[r];   // w == kp*2 + nt
        }
        __syncthreads();
        if (tid < 512){
            int nt2 = tid >> 8, idx = tid & 255;
            int col = nt2*16 + (idx & 15);
            float s = bias[col];
            #pragma unroll
            for (int kp2 = 0; kp2 < 8; kp2++) s += partS[(kp2*2 + nt2)*256 + idx];
            if (RELU) s = fmaxf(s, 0.f);
            int node = nodeS[idx >> 4];
            if (OUT_BF16)
                reinterpret_cast<ushort_t*>(yout)[(size_t)node*NOUT + col] = f_to_bf16(s);
            else
                reinterpret_cast<float*>(yout)[(size_t)node*NOUT + col] = s;
        }
    }
}

extern "C" void kernel_launch(void* const* d_in, const int* in_sizes, int n_in,
                              void* d_out, int out_size, void* d_ws, size_t ws_size,
                              hipStream_t stream){
    const int*   src   = (const int*)d_in[0];
    const int*   dst   = (const int*)d_in[1];
    const int*   etype = (const int*)d_in[2];
    const float* norm  = (const float*)d_in[3];
    const float* emb   = (const float*)d_in[4];
    const float* V1    = (const float*)d_in[5];
    const float* comp1 = (const float*)d_in[6];
    const float* bias1 = (const float*)d_in[7];
    const float* V2    = (const float*)d_in[8];
    const float* comp2 = (const float*)d_in[9];
    const float* bias2 = (const float*)d_in[10];
    float* out = (float*)d_out;

    char* w = (char*)d_ws;
    auto alloc = [&](size_t bytes) -> char* {
        char* p = w; w += (bytes + 255) & ~(size_t)255; return p;
    };
    int*      offsets = (int*)alloc((NN + 1) * 4);
    int*      counts  = (int*)alloc(NN * 4);
    int*      cursor  = (int*)alloc(NN * 4);
    int*      tot     = (int*)alloc(SC_B * 4);
    int*      dhist   = (int*)alloc(DEGB * 4);
    int*      dcur    = (int*)alloc(DEGB * 4);
    int*      perm    = (int*)alloc(NN * 4);
    int4*     meta    = (int4*)alloc((size_t)EE * 16);
    ushort_t* Wt1     = (ushort_t*)alloc((size_t)HH * KK * 2);
    ushort_t* Wt2     = (ushort_t*)alloc((size_t)OUTD * KK * 2);
    ushort_t* xb      = (ushort_t*)alloc((size_t)NN * HH * 2);
    ushort_t* h       = (ushort_t*)alloc((size_t)NN * HH * 2);

    // CSR build + payload sort + degree sort + weight/emb conversion
    zero_i32<<<(NN + 255)/256, 256, 0, stream>>>(counts, NN);
    zero_i32<<<1, 256, 0, stream>>>(dhist, DEGB);
    hist_kernel<<<(EE + 255)/256, 256, 0, stream>>>(dst, counts);
    scan_part<<<SC_B, 256, 0, stream>>>(counts, tot);
    scan_tot<<<1, 64, 0, stream>>>(tot);
    scan_final<<<SC_B, 256, 0, stream>>>(counts, tot, offsets, cursor);
    scatter_kernel<<<(EE + 255)/256, 256, 0, stream>>>(dst, src, etype, norm, cursor, meta);
    deg_hist_kernel<<<(NN + 255)/256, 256, 0, stream>>>(counts, dhist);
    deg_scan_kernel<<<1, 64, 0, stream>>>(dhist, dcur);
    deg_scatter_kernel<<<(NN + 255)/256, 256, 0, stream>>>(counts, dcur, perm);
    convw_kernel<<<((HH + OUTD)*KK + 255)/256, 256, 0, stream>>>(V1, V2, Wt1, Wt2);
    conv_emb<<<(NN*HH/2 + 255)/256, 256, 0, stream>>>(emb, xb);

    int nblocks = NN / NPB;  // 3125 exact
    // layer 1: xb (bf16) -> h (bf16, relu)
    fused_layer<HH, true, true><<<nblocks, 1024, 0, stream>>>(
        xb, meta, offsets, perm, comp1, Wt1, bias1, h);
    // layer 2: h (bf16) -> out (f32)
    fused_layer<OUTD, false, false><<<nblocks, 1024, 0, stream>>>(
        h, meta, offsets, perm, comp2, Wt2, bias2, out);
}

// Round 5
// 406.659 us; speedup vs baseline: 1.8088x; 1.8088x over previous
//
#include <hip/hip_runtime.h>
#include <hip/hip_bf16.h>

#define NN 50000
#define EE 600000
#define HH 128
#define OUTD 32
#define RR 64
#define BB 16
#define KK 2048   // BB*HH
#define NPB 16    // nodes per fused block (50000 = 16 * 3125 exactly)
#define SC_B ((NN + 1023) / 1024)  // 49 scan chunks

typedef short s16x8 __attribute__((ext_vector_type(8)));
typedef float f32x4 __attribute__((ext_vector_type(4)));
typedef unsigned short ushort_t;
typedef unsigned int uint_t;
typedef __attribute__((address_space(3))) uint_t lds_u32;
typedef const __attribute__((address_space(1))) uint_t glb_u32;

__device__ inline ushort_t f_to_bf16(float f){
    __hip_bfloat16 h = __float2bfloat16(f);
    return *reinterpret_cast<ushort_t*>(&h);
}
__device__ inline uint_t pack_bf16x2(float a, float b){
    return (uint_t)f_to_bf16(a) | ((uint_t)f_to_bf16(b) << 16);
}
__device__ inline float bf16_lo(uint_t u){ return __uint_as_float(u << 16); }
__device__ inline float bf16_hi(uint_t u){ return __uint_as_float(u & 0xffff0000u); }

__global__ void zero_i32(int* p, int n){
    int i = blockIdx.x*256 + threadIdx.x;
    if (i < n) p[i] = 0;
}

__global__ void hist_kernel(const int* __restrict__ dst, int* counts){
    int e = blockIdx.x*256 + threadIdx.x;
    if (e < EE) atomicAdd(&counts[dst[e]], 1);
}

// ---- hierarchical scan: chunk totals -> scan totals -> final ----
__global__ void scan_part(const int* __restrict__ counts, int* __restrict__ tot){
    int b = blockIdx.x, t = threadIdx.x;
    int i0 = b*1024 + t*4;
    int s = 0;
    if (i0 + 3 < NN){
        int4 v = *reinterpret_cast<const int4*>(&counts[i0]);
        s = v.x + v.y + v.z + v.w;
    } else {
        for (int j = 0; j < 4; j++) if (i0 + j < NN) s += counts[i0 + j];
    }
    #pragma unroll
    for (int off = 32; off; off >>= 1) s += __shfl_xor(s, off, 64);
    __shared__ int ws[4];
    if ((t & 63) == 0) ws[t >> 6] = s;
    __syncthreads();
    if (t == 0) tot[b] = ws[0] + ws[1] + ws[2] + ws[3];
}

__global__ void scan_tot(int* tot){  // 1 block, 64 threads (SC_B <= 64)
    int t = threadIdx.x;
    int v = (t < SC_B) ? tot[t] : 0;
    int x = v;
    #pragma unroll
    for (int off = 1; off < 64; off <<= 1){
        int y = __shfl_up(x, off, 64);
        if (t >= off) x += y;
    }
    if (t < SC_B) tot[t] = x - v;  // exclusive base per chunk
}

__global__ void scan_final(const int* __restrict__ counts, const int* __restrict__ tot,
                           int* __restrict__ offsets, int* __restrict__ cursor){
    int b = blockIdx.x, t = threadIdx.x, lane = t & 63, wv = t >> 6;
    int i0 = b*1024 + t*4;
    int v[4]; int s = 0;
    #pragma unroll
    for (int j = 0; j < 4; j++){ v[j] = (i0 + j < NN) ? counts[i0 + j] : 0; s += v[j]; }
    int x = s;
    #pragma unroll
    for (int off = 1; off < 64; off <<= 1){
        int y = __shfl_up(x, off, 64);
        if (lane >= off) x += y;
    }
    __shared__ int ws[4];
    if (lane == 63) ws[wv] = x;
    __syncthreads();
    int pre = tot[b];
    for (int i = 0; i < wv; i++) pre += ws[i];
    int run = pre + x - s;  // exclusive start of this thread's 4 elems
    #pragma unroll
    for (int j = 0; j < 4; j++){
        if (i0 + j < NN){
            cursor[i0 + j] = run;
            offsets[i0 + j + 1] = run + v[j];
        }
        run += v[j];
    }
    if (b == 0 && t == 0) offsets[0] = 0;
}

// scatter edge payload sorted by dst: meta[r] = {src, etype, norm_bits, 0}
__global__ void scatter_kernel(const int* __restrict__ dst, const int* __restrict__ src,
                               const int* __restrict__ etype, const float* __restrict__ norm,
                               int* cursor, int4* __restrict__ meta){
    int e = blockIdx.x*256 + threadIdx.x;
    if (e >= EE) return;
    int d = dst[e];
    int r = atomicAdd(&cursor[d], 1);
    int4 m;
    m.x = src[e];
    m.y = etype[e];
    m.z = __float_as_int(norm[e]);
    m.w = 0;
    meta[r] = m;
}

// transposed bf16 weights: Wt1[o][k] = V1[k][o] (k = b*H+i), Wt2[o][k] = V2[k][o]
__global__ void convw_kernel(const float* __restrict__ V1, const float* __restrict__ V2,
                             ushort_t* __restrict__ Wt1, ushort_t* __restrict__ Wt2){
    int i = blockIdx.x*256 + threadIdx.x;
    if (i < HH*KK){
        int o = i / KK, k = i % KK;
        Wt1[i] = f_to_bf16(V1[(size_t)k*HH + o]);
    } else {
        int j = i - HH*KK;
        if (j < OUTD*KK){
            int o = j / KK, k = j % KK;
            Wt2[j] = f_to_bf16(V2[(size_t)k*OUTD + o]);
        }
    }
}

__global__ void conv_emb(const float* __restrict__ emb, ushort_t* __restrict__ xb){
    int i = blockIdx.x*256 + threadIdx.x;
    if (i < NN*HH/2){
        float2 f = *reinterpret_cast<const float2*>(emb + 2*(size_t)i);
        *reinterpret_cast<uint_t*>(xb + 2*(size_t)i) = pack_bf16x2(f.x, f.y);
    }
}

// async DMA of one 256B x-row into a wave-private LDS ring slot
__device__ inline void issue_row(const ushort_t* xin, int srow, char* ldsdst, int lane){
    const uint_t* g = reinterpret_cast<const uint_t*>(xin + (size_t)srow*HH) + lane;
    __builtin_amdgcn_global_load_lds((glb_u32*)g, (lds_u32*)ldsdst, 4, 0, 0);
}

__device__ inline void consume_row(const char* slot, const float* comp, int e, float n,
                                   int lane, float* a0, float* a1){
    uint_t u = *reinterpret_cast<const uint_t*>(slot + lane*4);
    float xa = bf16_lo(u)*n, xb = bf16_hi(u)*n;
    const float* c = comp + e*BB;
    #pragma unroll
    for (int b = 0; b < BB; b++){
        a0[b] = fmaf(c[b], xa, a0[b]);
        a1[b] = fmaf(c[b], xb, a1[b]);
    }
}

// Fused per 16 nodes: wave w gathers node v0+w (async LDS-DMA, 3-deep batches)
// into a swizzled LDS bf16 row, then MFMA vs Wt.
// NOUT=128: wave -> (ct=w&7, kp=w>>3), 2 K-halves, reduce via LDS.
// NOUT=32 : wave -> (nt=w&1, kp=w>>1), 8 K-parts, reduce via LDS.
template<int NOUT, bool RELU, bool OUT_BF16>
__global__ __launch_bounds__(1024, 8) void fused_layer(
    const ushort_t* __restrict__ xin, const int4* __restrict__ meta,
    const int* __restrict__ offsets, const float* __restrict__ comp,
    const ushort_t* __restrict__ Wt, const float* __restrict__ bias,
    void* __restrict__ yout)
{
    __shared__ __align__(16) char ldsAll[NPB*4096 + NPB*768];
    char* aggS  = ldsAll;             // 16 rows x 4096B, XOR-swizzled
    char* ringS = ldsAll + NPB*4096;  // 16 waves x 3 slots x 256B

    int tid = threadIdx.x;
    int w = tid >> 6, lane = tid & 63;
    int v0 = blockIdx.x * NPB;
    int sv = __builtin_amdgcn_readfirstlane(v0 + w);   // wave-uniform node id
    int p0 = offsets[sv];
    int d  = offsets[sv + 1] - p0;
    char* ring = ringS + w*768;

    // ---- gather: batches of 3 edges, rows DMA'd into LDS, vmcnt(0) per batch ----
    float a0[BB], a1[BB];
    #pragma unroll
    for (int b = 0; b < BB; b++){ a0[b] = 0.f; a1[b] = 0.f; }

    for (int base = 0; base < d; base += 3){
        int i0 = p0 + base;
        int i1 = min(i0 + 1, EE - 1);
        int i2 = min(i0 + 2, EE - 1);
        int4 m0 = meta[i0];
        int4 m1 = meta[i1];
        int4 m2 = meta[i2];
        int s0 = __builtin_amdgcn_readfirstlane(m0.x);
        int s1 = __builtin_amdgcn_readfirstlane(m1.x);
        int s2 = __builtin_amdgcn_readfirstlane(m2.x);
        bool g1 = (base + 1 < d), g2 = (base + 2 < d);
        issue_row(xin, s0, ring, lane);
        if (g1) issue_row(xin, s1, ring + 256, lane);
        if (g2) issue_row(xin, s2, ring + 512, lane);
        asm volatile("s_waitcnt vmcnt(0)" ::: "memory");
        __builtin_amdgcn_sched_barrier(0);
        {
            int   e0 = __builtin_amdgcn_readfirstlane(m0.y);
            float n0 = __int_as_float(__builtin_amdgcn_readfirstlane(m0.z));
            consume_row(ring, comp, e0, n0, lane, a0, a1);
        }
        if (g1){
            int   e1 = __builtin_amdgcn_readfirstlane(m1.y);
            float n1 = __int_as_float(__builtin_amdgcn_readfirstlane(m1.z));
            consume_row(ring + 256, comp, e1, n1, lane, a0, a1);
        }
        if (g2){
            int   e2 = __builtin_amdgcn_readfirstlane(m2.y);
            float n2 = __int_as_float(__builtin_amdgcn_readfirstlane(m2.z));
            consume_row(ring + 512, comp, e2, n2, lane, a0, a1);
        }
    }

    // write agg row w (bf16x2 packed), XOR-swizzled so MFMA b128 reads are conflict-free
    {
        int swz = (w & 7) << 4;
        char* rowp = aggS + w*4096;
        #pragma unroll
        for (int b = 0; b < BB; b++)
            *reinterpret_cast<uint_t*>(rowp + ((b*256 + lane*4) ^ swz)) =
                pack_bf16x2(a0[b], a1[b]);
    }
    __syncthreads();

    // ---- GEMM phase ----
    int lane15 = lane & 15;
    int kc = (lane >> 4) * 8;            // element offset within 32-elem K-step
    float* partS = reinterpret_cast<float*>(ldsAll);  // aliases aggS AFTER MFMA reads

    if (NOUT == HH){
        int ct = w & 7, kp = w >> 3;     // 8 col-tiles x 2 K-halves (K=1024 each)
        f32x4 acc;
        #pragma unroll
        for (int j = 0; j < 4; j++) acc[j] = 0.f;
        const ushort_t* wrow = Wt + (size_t)(ct*16 + lane15)*KK + kp*1024 + kc;
        int abase = (kp*1024 + kc)*2;
        int rswz = (lane15 & 7) << 4;
        #pragma unroll 4
        for (int k = 0; k < 1024; k += 32){
            s16x8 a = *reinterpret_cast<const s16x8*>(
                aggS + lane15*4096 + ((abase + k*2) ^ rswz));
            s16x8 b = *reinterpret_cast<const s16x8*>(wrow + k);
            acc = __builtin_amdgcn_mfma_f32_16x16x32_bf16(a, b, acc, 0, 0, 0);
        }
        __syncthreads();
        if (kp == 1){
            #pragma unroll
            for (int r = 0; r < 4; r++){
                int idx = ((lane >> 4)*4 + r)*16 + lane15;
                partS[ct*256 + idx] = acc[r];
            }
        }
        __syncthreads();
        if (kp == 0){
            int col = ct*16 + lane15;
            float bv = bias[col];
            #pragma unroll
            for (int r = 0; r < 4; r++){
                int row = (lane >> 4)*4 + r;
                int idx = row*16 + lane15;
                float val = acc[r] + partS[ct*256 + idx] + bv;
                if (RELU) val = fmaxf(val, 0.f);
                if (OUT_BF16)
                    reinterpret_cast<ushort_t*>(yout)[(size_t)(v0 + row)*NOUT + col] = f_to_bf16(val);
                else
                    reinterpret_cast<float*>(yout)[(size_t)(v0 + row)*NOUT + col] = val;
            }
        }
    } else {
        int nt = w & 1, kp = w >> 1;     // 2 col-tiles x 8 K-parts (K=256 each)
        f32x4 acc;
        #pragma unroll
        for (int j = 0; j < 4; j++) acc[j] = 0.f;
        const ushort_t* wrow = Wt + (size_t)(nt*16 + lane15)*KK + kp*256 + kc;
        int abase = (kp*256 + kc)*2;
        int rswz = (lane15 & 7) << 4;
        #pragma unroll
        for (int k = 0; k < 256; k += 32){
            s16x8 a = *reinterpret_cast<const s16x8*>(
                aggS + lane15*4096 + ((abase + k*2) ^ rswz));
            s16x8 b = *reinterpret_cast<const s16x8*>(wrow + k);
            acc = __builtin_amdgcn_mfma_f32_16x16x32_bf16(a, b, acc, 0, 0, 0);
        }
        __syncthreads();
        #pragma unroll
        for (int r = 0; r < 4; r++){
            int idx = ((lane >> 4)*4 + r)*16 + lane15;
            partS[w*256 + idx] = acc[r];   // w == kp*2 + nt
        }
        __syncthreads();
        if (tid < 512){
            int nt2 = tid >> 8, idx = tid & 255;
            int col = nt2*16 + (idx & 15);
            float s = bias[col];
            #pragma unroll
            for (int kp2 = 0; kp2 < 8; kp2++) s += partS[(kp2*2 + nt2)*256 + idx];
            if (RELU) s = fmaxf(s, 0.f);
            int node = v0 + (idx >> 4);
            if (OUT_BF16)
                reinterpret_cast<ushort_t*>(yout)[(size_t)node*NOUT + col] = f_to_bf16(s);
            else
                reinterpret_cast<float*>(yout)[(size_t)node*NOUT + col] = s;
        }
    }
}

extern "C" void kernel_launch(void* const* d_in, const int* in_sizes, int n_in,
                              void* d_out, int out_size, void* d_ws, size_t ws_size,
                              hipStream_t stream){
    const int*   src   = (const int*)d_in[0];
    const int*   dst   = (const int*)d_in[1];
    const int*   etype = (const int*)d_in[2];
    const float* norm  = (const float*)d_in[3];
    const float* emb   = (const float*)d_in[4];
    const float* V1    = (const float*)d_in[5];
    const float* comp1 = (const float*)d_in[6];
    const float* bias1 = (const float*)d_in[7];
    const float* V2    = (const float*)d_in[8];
    const float* comp2 = (const float*)d_in[9];
    const float* bias2 = (const float*)d_in[10];
    float* out = (float*)d_out;

    char* w = (char*)d_ws;
    auto alloc = [&](size_t bytes) -> char* {
        char* p = w; w += (bytes + 255) & ~(size_t)255; return p;
    };
    int*      offsets = (int*)alloc((NN + 1) * 4);
    int*      counts  = (int*)alloc(NN * 4);
    int*      cursor  = (int*)alloc(NN * 4);
    int*      tot     = (int*)alloc(SC_B * 4);
    int4*     meta    = (int4*)alloc((size_t)EE * 16);
    ushort_t* Wt1     = (ushort_t*)alloc((size_t)HH * KK * 2);
    ushort_t* Wt2     = (ushort_t*)alloc((size_t)OUTD * KK * 2);
    ushort_t* xb      = (ushort_t*)alloc((size_t)NN * HH * 2);
    ushort_t* h       = (ushort_t*)alloc((size_t)NN * HH * 2);

    // CSR build + payload sort + weight/emb conversion
    zero_i32<<<(NN + 255)/256, 256, 0, stream>>>(counts, NN);
    hist_kernel<<<(EE + 255)/256, 256, 0, stream>>>(dst, counts);
    scan_part<<<SC_B, 256, 0, stream>>>(counts, tot);
    scan_tot<<<1, 64, 0, stream>>>(tot);
    scan_final<<<SC_B, 256, 0, stream>>>(counts, tot, offsets, cursor);
    scatter_kernel<<<(EE + 255)/256, 256, 0, stream>>>(dst, src, etype, norm, cursor, meta);
    convw_kernel<<<((HH + OUTD)*KK + 255)/256, 256, 0, stream>>>(V1, V2, Wt1, Wt2);
    conv_emb<<<(NN*HH/2 + 255)/256, 256, 0, stream>>>(emb, xb);

    int nblocks = NN / NPB;  // 3125 exact
    // layer 1: xb (bf16) -> h (bf16, relu)
    fused_layer<HH, true, true><<<nblocks, 1024, 0, stream>>>(
        xb, meta, offsets, comp1, Wt1, bias1, h);
    // layer 2: h (bf16) -> out (f32)
    fused_layer<OUTD, false, false><<<nblocks, 1024, 0, stream>>>(
        h, meta, offsets, comp2, Wt2, bias2, out);
}

// Round 6
// 406.494 us; speedup vs baseline: 1.8095x; 1.0004x over previous
//
#include <hip/hip_runtime.h>
#include <hip/hip_bf16.h>

#define NN 50000
#define EE 600000
#define HH 128
#define OUTD 32
#define RR 64
#define BB 16
#define KK 2048   // BB*HH
#define NPB 16    // nodes per fused block (50000 = 16 * 3125 exactly)
#define SC_B ((NN + 1023) / 1024)  // 49 scan chunks

typedef short s16x8 __attribute__((ext_vector_type(8)));
typedef float f32x4 __attribute__((ext_vector_type(4)));
typedef unsigned short ushort_t;
typedef unsigned int uint_t;
typedef __attribute__((address_space(3))) uint_t lds_u32;
typedef const __attribute__((address_space(1))) uint_t glb_u32;

__device__ inline ushort_t f_to_bf16(float f){
    __hip_bfloat16 h = __float2bfloat16(f);
    return *reinterpret_cast<ushort_t*>(&h);
}
__device__ inline uint_t pack_bf16x2(float a, float b){
    return (uint_t)f_to_bf16(a) | ((uint_t)f_to_bf16(b) << 16);
}
__device__ inline float bf16_lo(uint_t u){ return __uint_as_float(u << 16); }
__device__ inline float bf16_hi(uint_t u){ return __uint_as_float(u & 0xffff0000u); }

__global__ void zero_i32(int* p, int n){
    int i = blockIdx.x*256 + threadIdx.x;
    if (i < n) p[i] = 0;
}

__global__ void hist_kernel(const int* __restrict__ dst, int* counts){
    int e = blockIdx.x*256 + threadIdx.x;
    if (e < EE) atomicAdd(&counts[dst[e]], 1);
}

// ---- hierarchical scan: chunk totals -> scan totals -> final ----
__global__ void scan_part(const int* __restrict__ counts, int* __restrict__ tot){
    int b = blockIdx.x, t = threadIdx.x;
    int i0 = b*1024 + t*4;
    int s = 0;
    if (i0 + 3 < NN){
        int4 v = *reinterpret_cast<const int4*>(&counts[i0]);
        s = v.x + v.y + v.z + v.w;
    } else {
        for (int j = 0; j < 4; j++) if (i0 + j < NN) s += counts[i0 + j];
    }
    #pragma unroll
    for (int off = 32; off; off >>= 1) s += __shfl_xor(s, off, 64);
    __shared__ int ws[4];
    if ((t & 63) == 0) ws[t >> 6] = s;
    __syncthreads();
    if (t == 0) tot[b] = ws[0] + ws[1] + ws[2] + ws[3];
}

__global__ void scan_tot(int* tot){  // 1 block, 64 threads (SC_B <= 64)
    int t = threadIdx.x;
    int v = (t < SC_B) ? tot[t] : 0;
    int x = v;
    #pragma unroll
    for (int off = 1; off < 64; off <<= 1){
        int y = __shfl_up(x, off, 64);
        if (t >= off) x += y;
    }
    if (t < SC_B) tot[t] = x - v;  // exclusive base per chunk
}

__global__ void scan_final(const int* __restrict__ counts, const int* __restrict__ tot,
                           int* __restrict__ offsets, int* __restrict__ cursor){
    int b = blockIdx.x, t = threadIdx.x, lane = t & 63, wv = t >> 6;
    int i0 = b*1024 + t*4;
    int v[4]; int s = 0;
    #pragma unroll
    for (int j = 0; j < 4; j++){ v[j] = (i0 + j < NN) ? counts[i0 + j] : 0; s += v[j]; }
    int x = s;
    #pragma unroll
    for (int off = 1; off < 64; off <<= 1){
        int y = __shfl_up(x, off, 64);
        if (lane >= off) x += y;
    }
    __shared__ int ws[4];
    if (lane == 63) ws[wv] = x;
    __syncthreads();
    int pre = tot[b];
    for (int i = 0; i < wv; i++) pre += ws[i];
    int run = pre + x - s;  // exclusive start of this thread's 4 elems
    #pragma unroll
    for (int j = 0; j < 4; j++){
        if (i0 + j < NN){
            cursor[i0 + j] = run;
            offsets[i0 + j + 1] = run + v[j];
        }
        run += v[j];
    }
    if (b == 0 && t == 0) offsets[0] = 0;
}

// scatter edge payload sorted by dst: meta[r] = {src, etype, norm_bits, 0}
__global__ void scatter_kernel(const int* __restrict__ dst, const int* __restrict__ src,
                               const int* __restrict__ etype, const float* __restrict__ norm,
                               int* cursor, int4* __restrict__ meta){
    int e = blockIdx.x*256 + threadIdx.x;
    if (e >= EE) return;
    int d = dst[e];
    int r = atomicAdd(&cursor[d], 1);
    int4 m;
    m.x = src[e];
    m.y = etype[e];
    m.z = __float_as_int(norm[e]);
    m.w = 0;
    meta[r] = m;
}

// transposed bf16 weights: Wt1[o][k] = V1[k][o] (k = b*H+i), Wt2[o][k] = V2[k][o]
__global__ void convw_kernel(const float* __restrict__ V1, const float* __restrict__ V2,
                             ushort_t* __restrict__ Wt1, ushort_t* __restrict__ Wt2){
    int i = blockIdx.x*256 + threadIdx.x;
    if (i < HH*KK){
        int o = i / KK, k = i % KK;
        Wt1[i] = f_to_bf16(V1[(size_t)k*HH + o]);
    } else {
        int j = i - HH*KK;
        if (j < OUTD*KK){
            int o = j / KK, k = j % KK;
            Wt2[j] = f_to_bf16(V2[(size_t)k*OUTD + o]);
        }
    }
}

__global__ void conv_emb(const float* __restrict__ emb, ushort_t* __restrict__ xb){
    int i = blockIdx.x*256 + threadIdx.x;
    if (i < NN*HH/2){
        float2 f = *reinterpret_cast<const float2*>(emb + 2*(size_t)i);
        *reinterpret_cast<uint_t*>(xb + 2*(size_t)i) = pack_bf16x2(f.x, f.y);
    }
}

// async DMA of one 256B x-row into a wave-private LDS ring slot
__device__ inline void issue_row(const ushort_t* xin, int srow, char* ldsdst, int lane){
    const uint_t* g = reinterpret_cast<const uint_t*>(xin + (size_t)srow*HH) + lane;
    __builtin_amdgcn_global_load_lds((glb_u32*)g, (lds_u32*)ldsdst, 4, 0, 0);
}

__device__ inline void consume_row(const char* slot, const float* comp, int e, float n,
                                   int lane, float* a0, float* a1){
    uint_t u = *reinterpret_cast<const uint_t*>(slot + lane*4);
    float xa = bf16_lo(u)*n, xb = bf16_hi(u)*n;
    const float* c = comp + e*BB;   // uniform -> scalar loads
    #pragma unroll
    for (int b = 0; b < BB; b++){
        a0[b] = fmaf(c[b], xa, a0[b]);
        a1[b] = fmaf(c[b], xb, a1[b]);
    }
}

// Fused per 16 nodes: wave w gathers node v0+w via a CONTINUOUS depth-3
// LDS-DMA pipeline (counted vmcnt, never drained in steady state); edge
// metadata register-resident via one coalesced load + readlane.
// Then MFMA vs Wt. NOUT=128: wave -> (ct=w&7, kp=w>>3), 2 K-halves, LDS reduce.
// NOUT=32 : wave -> (nt=w&1, kp=w>>1), 8 K-parts, LDS reduce.
template<int NOUT, bool RELU, bool OUT_BF16>
__global__ __launch_bounds__(1024, 8) void fused_layer(
    const ushort_t* __restrict__ xin, const int4* __restrict__ meta,
    const int* __restrict__ offsets, const float* __restrict__ comp,
    const ushort_t* __restrict__ Wt, const float* __restrict__ bias,
    void* __restrict__ yout)
{
    __shared__ __align__(16) char ldsAll[NPB*4096 + NPB*1024];  // 64KB agg + 16KB ring
    char* aggS  = ldsAll;             // 16 rows x 4096B, XOR-swizzled
    char* ringS = ldsAll + NPB*4096;  // 16 waves x 4 slots x 256B

    int tid = threadIdx.x;
    int w = tid >> 6, lane = tid & 63;
    int v0 = blockIdx.x * NPB;
    int sv = v0 + w;                   // wave-uniform node id
    int p0 = offsets[sv];
    int dd = offsets[sv + 1] - p0;
    char* ring = ringS + w*1024;

    float a0[BB], a1[BB];
    #pragma unroll
    for (int b = 0; b < BB; b++){ a0[b] = 0.f; a1[b] = 0.f; }

    // ---- gather: chunks of <=64 edges; metas in registers; 3 rows in flight ----
    for (int c0 = 0; c0 < dd; c0 += 64){
        int nc = min(64, dd - c0);
        int4 mv = meta[p0 + c0 + min(lane, nc - 1)];  // lane e holds meta of edge e
        {   // prologue: fill pipeline (clamped dup issues are harmless)
            int s0 = __builtin_amdgcn_readlane(mv.x, 0);
            issue_row(xin, s0, ring + 0*256, lane);
            int s1 = __builtin_amdgcn_readlane(mv.x, min(1, nc - 1));
            issue_row(xin, s1, ring + 1*256, lane);
            int s2 = __builtin_amdgcn_readlane(mv.x, min(2, nc - 1));
            issue_row(xin, s2, ring + 2*256, lane);
        }
        for (int e = 0; e < nc; ++e){
            asm volatile("s_waitcnt vmcnt(2)" ::: "memory");  // oldest row landed
            int   ee = __builtin_amdgcn_readlane(mv.y, e);
            float nn = __int_as_float(__builtin_amdgcn_readlane(mv.z, e));
            consume_row(ring + (e & 3)*256, comp, ee, nn, lane, a0, a1);
            int sn = __builtin_amdgcn_readlane(mv.x, min(e + 3, nc - 1));
            issue_row(xin, sn, ring + ((e + 3) & 3)*256, lane);
        }
        if (c0 + 64 < dd)  // rare (degree > 64): drain so slot writes can't collide
            asm volatile("s_waitcnt vmcnt(0)" ::: "memory");
    }

    // write agg row w (bf16x2 packed), XOR-swizzled so MFMA b128 reads are conflict-free
    {
        int swz = (w & 7) << 4;
        char* rowp = aggS + w*4096;
        #pragma unroll
        for (int b = 0; b < BB; b++)
            *reinterpret_cast<uint_t*>(rowp + ((b*256 + lane*4) ^ swz)) =
                pack_bf16x2(a0[b], a1[b]);
    }
    __syncthreads();

    // ---- GEMM phase ----
    int lane15 = lane & 15;
    int kc = (lane >> 4) * 8;            // element offset within 32-elem K-step
    float* partS = reinterpret_cast<float*>(ldsAll);  // aliases aggS AFTER MFMA reads

    if (NOUT == HH){
        int ct = w & 7, kp = w >> 3;     // 8 col-tiles x 2 K-halves (K=1024 each)
        f32x4 acc;
        #pragma unroll
        for (int j = 0; j < 4; j++) acc[j] = 0.f;
        const ushort_t* wrow = Wt + (size_t)(ct*16 + lane15)*KK + kp*1024 + kc;
        int abase = (kp*1024 + kc)*2;
        int rswz = (lane15 & 7) << 4;
        #pragma unroll 4
        for (int k = 0; k < 1024; k += 32){
            s16x8 a = *reinterpret_cast<const s16x8*>(
                aggS + lane15*4096 + ((abase + k*2) ^ rswz));
            s16x8 b = *reinterpret_cast<const s16x8*>(wrow + k);
            acc = __builtin_amdgcn_mfma_f32_16x16x32_bf16(a, b, acc, 0, 0, 0);
        }
        __syncthreads();
        if (kp == 1){
            #pragma unroll
            for (int r = 0; r < 4; r++){
                int idx = ((lane >> 4)*4 + r)*16 + lane15;
                partS[ct*256 + idx] = acc[r];
            }
        }
        __syncthreads();
        if (kp == 0){
            int col = ct*16 + lane15;
            float bv = bias[col];
            #pragma unroll
            for (int r = 0; r < 4; r++){
                int row = (lane >> 4)*4 + r;
                int idx = row*16 + lane15;
                float val = acc[r] + partS[ct*256 + idx] + bv;
                if (RELU) val = fmaxf(val, 0.f);
                if (OUT_BF16)
                    reinterpret_cast<ushort_t*>(yout)[(size_t)(v0 + row)*NOUT + col] = f_to_bf16(val);
                else
                    reinterpret_cast<float*>(yout)[(size_t)(v0 + row)*NOUT + col] = val;
            }
        }
    } else {
        int nt = w & 1, kp = w >> 1;     // 2 col-tiles x 8 K-parts (K=256 each)
        f32x4 acc;
        #pragma unroll
        for (int j = 0; j < 4; j++) acc[j] = 0.f;
        const ushort_t* wrow = Wt + (size_t)(nt*16 + lane15)*KK + kp*256 + kc;
        int abase = (kp*256 + kc)*2;
        int rswz = (lane15 & 7) << 4;
        #pragma unroll
        for (int k = 0; k < 256; k += 32){
            s16x8 a = *reinterpret_cast<const s16x8*>(
                aggS + lane15*4096 + ((abase + k*2) ^ rswz));
            s16x8 b = *reinterpret_cast<const s16x8*>(wrow + k);
            acc = __builtin_amdgcn_mfma_f32_16x16x32_bf16(a, b, acc, 0, 0, 0);
        }
        __syncthreads();
        #pragma unroll
        for (int r = 0; r < 4; r++){
            int idx = ((lane >> 4)*4 + r)*16 + lane15;
            partS[w*256 + idx] = acc[r];   // w == kp*2 + nt
        }
        __syncthreads();
        if (tid < 512){
            int nt2 = tid >> 8, idx = tid & 255;
            int col = nt2*16 + (idx & 15);
            float s = bias[col];
            #pragma unroll
            for (int kp2 = 0; kp2 < 8; kp2++) s += partS[(kp2*2 + nt2)*256 + idx];
            if (RELU) s = fmaxf(s, 0.f);
            int node = v0 + (idx >> 4);
            if (OUT_BF16)
                reinterpret_cast<ushort_t*>(yout)[(size_t)node*NOUT + col] = f_to_bf16(s);
            else
                reinterpret_cast<float*>(yout)[(size_t)node*NOUT + col] = s;
        }
    }
}

extern "C" void kernel_launch(void* const* d_in, const int* in_sizes, int n_in,
                              void* d_out, int out_size, void* d_ws, size_t ws_size,
                              hipStream_t stream){
    const int*   src   = (const int*)d_in[0];
    const int*   dst   = (const int*)d_in[1];
    const int*   etype = (const int*)d_in[2];
    const float* norm  = (const float*)d_in[3];
    const float* emb   = (const float*)d_in[4];
    const float* V1    = (const float*)d_in[5];
    const float* comp1 = (const float*)d_in[6];
    const float* bias1 = (const float*)d_in[7];
    const float* V2    = (const float*)d_in[8];
    const float* comp2 = (const float*)d_in[9];
    const float* bias2 = (const float*)d_in[10];
    float* out = (float*)d_out;

    char* w = (char*)d_ws;
    auto alloc = [&](size_t bytes) -> char* {
        char* p = w; w += (bytes + 255) & ~(size_t)255; return p;
    };
    int*      offsets = (int*)alloc((NN + 1) * 4);
    int*      counts  = (int*)alloc(NN * 4);
    int*      cursor  = (int*)alloc(NN * 4);
    int*      tot     = (int*)alloc(SC_B * 4);
    int4*     meta    = (int4*)alloc((size_t)EE * 16);
    ushort_t* Wt1     = (ushort_t*)alloc((size_t)HH * KK * 2);
    ushort_t* Wt2     = (ushort_t*)alloc((size_t)OUTD * KK * 2);
    ushort_t* xb      = (ushort_t*)alloc((size_t)NN * HH * 2);
    ushort_t* h       = (ushort_t*)alloc((size_t)NN * HH * 2);

    // CSR build + payload sort + weight/emb conversion
    zero_i32<<<(NN + 255)/256, 256, 0, stream>>>(counts, NN);
    hist_kernel<<<(EE + 255)/256, 256, 0, stream>>>(dst, counts);
    scan_part<<<SC_B, 256, 0, stream>>>(counts, tot);
    scan_tot<<<1, 64, 0, stream>>>(tot);
    scan_final<<<SC_B, 256, 0, stream>>>(counts, tot, offsets, cursor);
    scatter_kernel<<<(EE + 255)/256, 256, 0, stream>>>(dst, src, etype, norm, cursor, meta);
    convw_kernel<<<((HH + OUTD)*KK + 255)/256, 256, 0, stream>>>(V1, V2, Wt1, Wt2);
    conv_emb<<<(NN*HH/2 + 255)/256, 256, 0, stream>>>(emb, xb);

    int nblocks = NN / NPB;  // 3125 exact
    // layer 1: xb (bf16) -> h (bf16, relu)
    fused_layer<HH, true, true><<<nblocks, 1024, 0, stream>>>(
        xb, meta, offsets, comp1, Wt1, bias1, h);
    // layer 2: h (bf16) -> out (f32)
    fused_layer<OUTD, false, false><<<nblocks, 1024, 0, stream>>>(
        h, meta, offsets, comp2, Wt2, bias2, out);
}